// Round 7
// baseline (528.397 us; speedup 1.0000x reference)
//
#include <hip/hip_runtime.h>
#include <hip/hip_bf16.h>

typedef float f32x4 __attribute__((ext_vector_type(4)));
typedef short bf16x8 __attribute__((ext_vector_type(8)));
typedef unsigned short ushort;

// 256^2 GEMM geometry, register-pipelined, 1 barrier per K-tile
#define BM 256
#define BN 256
#define BK 64

// ---------- helpers ----------

__device__ inline ushort f2bf(float f) {
    __hip_bfloat16 h = __float2bfloat16(f);   // RNE
    ushort s;
    __builtin_memcpy(&s, &h, 2);
    return s;
}

__device__ inline bf16x8 quant_pack8(float4 a, float4 b, float inv_scale, float zp) {
    float v[8] = {a.x, a.y, a.z, a.w, b.x, b.y, b.z, b.w};
    union { bf16x8 v8; ushort s[8]; } o;
#pragma unroll
    for (int j = 0; j < 8; ++j) {
        float t = rintf(fmaf(v[j], inv_scale, zp));
        t = fminf(127.0f, fmaxf(-128.0f, t));
        o.s[j] = f2bf(t);
    }
    return o.v8;
}

__device__ inline bf16x8 cvt_pack8(float4 a, float4 b) {
    float v[8] = {a.x, a.y, a.z, a.w, b.x, b.y, b.z, b.w};
    union { bf16x8 v8; ushort s[8]; } o;
#pragma unroll
    for (int j = 0; j < 8; ++j) o.s[j] = f2bf(v[j]);
    return o.v8;
}

#define GLL16(gp, lp)                                                              \
    __builtin_amdgcn_global_load_lds(                                              \
        (const __attribute__((address_space(1))) unsigned int*)(gp),               \
        (__attribute__((address_space(3))) unsigned int*)(lp), 16, 0, 0)

__device__ inline bf16x8 lds_read_b128(const ushort* p) {
    bf16x8 r;
    const __attribute__((address_space(3))) ushort* lp =
        (const __attribute__((address_space(3))) ushort*)p;
    asm volatile("ds_read_b128 %0, %1" : "=&v"(r) : "v"(lp));
    return r;
}

#define SB0() __builtin_amdgcn_sched_barrier(0)
#define WAIT_LGKM(n) asm volatile("s_waitcnt lgkmcnt(" #n ")" ::: "memory")

// ---------- kernel 1: per-block min/max partials ----------

__global__ __launch_bounds__(256) void minmax_partial(const float* __restrict__ x, int n4,
                                                      float* __restrict__ pmin,
                                                      float* __restrict__ pmax) {
    float lmin = 3.4e38f, lmax = -3.4e38f;
    const float4* xv = (const float4*)x;
    int stride = gridDim.x * blockDim.x;
    for (int i = blockIdx.x * blockDim.x + threadIdx.x; i < n4; i += stride) {
        float4 v = xv[i];
        lmin = fminf(lmin, fminf(fminf(v.x, v.y), fminf(v.z, v.w)));
        lmax = fmaxf(lmax, fmaxf(fmaxf(v.x, v.y), fmaxf(v.z, v.w)));
    }
#pragma unroll
    for (int off = 32; off > 0; off >>= 1) {
        lmin = fminf(lmin, __shfl_down(lmin, off));
        lmax = fmaxf(lmax, __shfl_down(lmax, off));
    }
    __shared__ float smin[4], smax[4];
    int w = threadIdx.x >> 6;
    if ((threadIdx.x & 63) == 0) { smin[w] = lmin; smax[w] = lmax; }
    __syncthreads();
    if (threadIdx.x == 0) {
        pmin[blockIdx.x] = fminf(fminf(smin[0], smin[1]), fminf(smin[2], smin[3]));
        pmax[blockIdx.x] = fmaxf(fmaxf(smax[0], smax[1]), fmaxf(smax[2], smax[3]));
    }
}

// ---------- kernel 2: finalize scale/zp ----------

__global__ __launch_bounds__(64) void finalize_qp(const float* __restrict__ pmin,
                                                  const float* __restrict__ pmax, int nb,
                                                  float* __restrict__ hdr) {
    float lmin = 3.4e38f, lmax = -3.4e38f;
    for (int i = threadIdx.x; i < nb; i += 64) {
        lmin = fminf(lmin, pmin[i]);
        lmax = fmaxf(lmax, pmax[i]);
    }
#pragma unroll
    for (int off = 32; off > 0; off >>= 1) {
        lmin = fminf(lmin, __shfl_down(lmin, off));
        lmax = fmaxf(lmax, __shfl_down(lmax, off));
    }
    if (threadIdx.x == 0) {
        float scale = (lmax - lmin) / 255.0f;
        float zp = -128.0f - rintf(lmin / scale);
        zp = fminf(127.0f, fmaxf(-128.0f, zp));
        hdr[0] = 1.0f / scale;
        hdr[1] = zp;
    }
}

// ---------- kernel 3a: quantize x -> bf16 codes ----------

__global__ __launch_bounds__(256) void quant_x_kernel(const float* __restrict__ x,
                                                      ushort* __restrict__ xq,
                                                      const float* __restrict__ qp, int n8) {
    const float inv_scale = qp[0];
    const float zp = qp[1];
    int stride = gridDim.x * blockDim.x;
    for (int i = blockIdx.x * blockDim.x + threadIdx.x; i < n8; i += stride) {
        float4 a = *(const float4*)(x + (size_t)i * 8);
        float4 b = *(const float4*)(x + (size_t)i * 8 + 4);
        *(bf16x8*)(xq + (size_t)i * 8) = quant_pack8(a, b, inv_scale, zp);
    }
}

// ---------- kernel 3b: convert W -> bf16 ----------

__global__ __launch_bounds__(256) void cvt_w_kernel(const float* __restrict__ w,
                                                    ushort* __restrict__ wq, int n8) {
    int stride = gridDim.x * blockDim.x;
    for (int i = blockIdx.x * blockDim.x + threadIdx.x; i < n8; i += stride) {
        float4 a = *(const float4*)(w + (size_t)i * 8);
        float4 b = *(const float4*)(w + (size_t)i * 8 + 4);
        *(bf16x8*)(wq + (size_t)i * 8) = cvt_pack8(a, b);
    }
}

// ---------- kernel 4: 256x256 bf16 MFMA GEMM, register-pipelined ----------
// C = A(MxK) * B(NxK)^T + bias.
// 512 thr = 8 waves (2x4), wave tile 128x64 = 8x4 frags of 16x16x32.
// Per K-tile: 4 MFMA clusters of 16; all ds_reads issued one cluster AHEAD,
// waited with exact counted lgkmcnt (in-order DS completion). No intra-tile
// barriers: waves free-run so DS bursts overlap other waves' MFMA. One
// vmcnt(0)+s_barrier per tile (waits loads issued a full tile earlier).
// Stage(t+1) at tile top into buf^1 (its prior readers drained lgkm before
// the previous barrier -> race-free).

__global__ __launch_bounds__(512, 2) void gemm_bt(const ushort* __restrict__ A,
                                                  const ushort* __restrict__ Bw,
                                                  const float* __restrict__ bias,
                                                  float* __restrict__ out,
                                                  int M, int N, int K) {
    __shared__ ushort Alds[2 * 16384];  // [buf][kg 0..7][row 0..255][8] = 64 KB
    __shared__ ushort Blds[2 * 16384];  // 64 KB

    const int tid = threadIdx.x;
    const int lane = tid & 63;
    const int wid = tid >> 6;

    // bijective XCD swizzle (nwg % 8 == 0 guaranteed by launcher)
    const int nwg = gridDim.x;
    const int cpx = nwg >> 3;
    const int swz = (blockIdx.x & 7) * cpx + (blockIdx.x >> 3);
    const int nbn = N / BN;
    const int bm = (swz / nbn) * BM;
    const int bn = (swz % nbn) * BN;

    const int wm = (wid >> 2) * 128;  // wave row offset
    const int wn = (wid & 3) * 64;    // wave col offset
    const int l16 = lane & 15;
    const int l4 = lane >> 4;

    // staging ownership
    const int r0 = tid & 255;
    const int kgl0 = tid >> 8;        // 0 or 1; wave-uniform
    const ushort* gA = A  + (size_t)(bm + r0) * K + kgl0 * 8;
    const ushort* gB = Bw + (size_t)(bn + r0) * K + kgl0 * 8;
    const int dst0 = kgl0 * 2048 + r0 * 8;

    // stage one full K-tile (A+B, 8 GLL16/thread) into buffer b at k-offset ko
#define STAGE_TILE(b, ko)                                                    \
    {                                                                        \
        _Pragma("unroll")                                                    \
        for (int kh_ = 0; kh_ < 2; ++kh_) {                                  \
            ushort* dA_ = Alds + (b) * 16384 + kh_ * 8192 + dst0;            \
            const ushort* sA_ = gA + (ko) + kh_ * 32;                        \
            GLL16(sA_, dA_);                                                 \
            GLL16(sA_ + 16, dA_ + 4096);                                     \
            ushort* dB_ = Blds + (b) * 16384 + kh_ * 8192 + dst0;            \
            const ushort* sB_ = gB + (ko) + kh_ * 32;                        \
            GLL16(sB_, dB_);                                                 \
            GLL16(sB_ + 16, dB_ + 4096);                                     \
        }                                                                    \
    }

    f32x4 acc[8][4];
#pragma unroll
    for (int i = 0; i < 8; ++i)
#pragma unroll
        for (int j = 0; j < 4; ++j) acc[i][j] = (f32x4){0.f, 0.f, 0.f, 0.f};

    const int nk = K / BK;

    // ---- prologue: stage tile0 only
    STAGE_TILE(0, 0);
    asm volatile("s_waitcnt vmcnt(0)" ::: "memory");
    __builtin_amdgcn_s_barrier();

    // per-wave LDS read bases (ushort units)
    const ushort* aBase = Alds + l4 * 2048 + (wm + l16) * 8;
    const ushort* bBase = Blds + l4 * 2048 + (wn + l16) * 8;

    bf16x8 af[8], ag[8];
    bf16x8 bA0, bA1, bB0, bB1, bC0, bC1, bD0, bD1;

    for (int t = 0; t < nk; ++t) {
        const int buf = t & 1;
        const ushort* aRd = aBase + buf * 16384;
        const ushort* bRd = bBase + buf * 16384;

        // R0: A-ks0 (8) + B-ks0-fj01 (2)
#pragma unroll
        for (int fi = 0; fi < 8; ++fi) af[fi] = lds_read_b128(aRd + fi * 128);
        bA0 = lds_read_b128(bRd + 0 * 128);
        bA1 = lds_read_b128(bRd + 1 * 128);
        // R1: B-ks0-fj23 (2)
        bB0 = lds_read_b128(bRd + 2 * 128);
        bB1 = lds_read_b128(bRd + 3 * 128);
        // stage next tile (other buffer; prior readers drained before last barrier)
        if (t + 1 < nk) STAGE_TILE(buf ^ 1, (t + 1) * 64);

        WAIT_LGKM(2);            // R0 landed (12 outstanding -> 2)
        SB0();
        __builtin_amdgcn_s_setprio(1);
#pragma unroll
        for (int fi = 0; fi < 8; ++fi) {
            acc[fi][0] = __builtin_amdgcn_mfma_f32_16x16x32_bf16(af[fi], bA0, acc[fi][0], 0, 0, 0);
            acc[fi][1] = __builtin_amdgcn_mfma_f32_16x16x32_bf16(af[fi], bA1, acc[fi][1], 0, 0, 0);
        }
        __builtin_amdgcn_s_setprio(0);
        SB0();

        // R2: A-ks1 (8) + B-ks1-fj01 (2)
#pragma unroll
        for (int fi = 0; fi < 8; ++fi) ag[fi] = lds_read_b128(aRd + 8192 + fi * 128);
        bC0 = lds_read_b128(bRd + 8192 + 0 * 128);
        bC1 = lds_read_b128(bRd + 8192 + 1 * 128);

        WAIT_LGKM(10);           // R1 landed (12 outstanding -> 10)
        SB0();
        __builtin_amdgcn_s_setprio(1);
#pragma unroll
        for (int fi = 0; fi < 8; ++fi) {
            acc[fi][2] = __builtin_amdgcn_mfma_f32_16x16x32_bf16(af[fi], bB0, acc[fi][2], 0, 0, 0);
            acc[fi][3] = __builtin_amdgcn_mfma_f32_16x16x32_bf16(af[fi], bB1, acc[fi][3], 0, 0, 0);
        }
        __builtin_amdgcn_s_setprio(0);
        SB0();

        // R3: B-ks1-fj23 (2)
        bD0 = lds_read_b128(bRd + 8192 + 2 * 128);
        bD1 = lds_read_b128(bRd + 8192 + 3 * 128);

        WAIT_LGKM(2);            // R2 landed (12 outstanding -> 2)
        SB0();
        __builtin_amdgcn_s_setprio(1);
#pragma unroll
        for (int fi = 0; fi < 8; ++fi) {
            acc[fi][0] = __builtin_amdgcn_mfma_f32_16x16x32_bf16(ag[fi], bC0, acc[fi][0], 0, 0, 0);
            acc[fi][1] = __builtin_amdgcn_mfma_f32_16x16x32_bf16(ag[fi], bC1, acc[fi][1], 0, 0, 0);
        }
        __builtin_amdgcn_s_setprio(0);
        SB0();

        WAIT_LGKM(0);            // R3 landed
        SB0();
        __builtin_amdgcn_s_setprio(1);
#pragma unroll
        for (int fi = 0; fi < 8; ++fi) {
            acc[fi][2] = __builtin_amdgcn_mfma_f32_16x16x32_bf16(ag[fi], bD0, acc[fi][2], 0, 0, 0);
            acc[fi][3] = __builtin_amdgcn_mfma_f32_16x16x32_bf16(ag[fi], bD1, acc[fi][3], 0, 0, 0);
        }
        __builtin_amdgcn_s_setprio(0);
        SB0();

        // tile boundary: next tile's DMA (issued at this tile's top) must be
        // visible to ALL waves -> per-wave vmcnt(0) then barrier.
        asm volatile("s_waitcnt vmcnt(0)" ::: "memory");
        __builtin_amdgcn_s_barrier();
    }
#undef STAGE_TILE

    // epilogue: C/D layout col = lane&15, row = (lane>>4)*4 + r
#pragma unroll
    for (int fj = 0; fj < 4; ++fj) {
        const int col = bn + wn + fj * 16 + l16;
        const float bj = bias[col];
#pragma unroll
        for (int fi = 0; fi < 8; ++fi) {
            const int rowb = bm + wm + fi * 16 + l4 * 4;
            float* po = out + (size_t)rowb * N + col;
#pragma unroll
            for (int r = 0; r < 4; ++r) po[(size_t)r * N] = acc[fi][fj][r] + bj;
        }
    }
}

// ---------- fallback: fused quantize+GEMM (128^2, used if ws too small) ----------

__global__ __launch_bounds__(256) void qgemm_fused(const float* __restrict__ x,
                                                   const float* __restrict__ w,
                                                   const float* __restrict__ bias,
                                                   const float* __restrict__ qp,
                                                   float* __restrict__ out,
                                                   int M, int N, int K) {
    __shared__ ushort As[4][128][8];
    __shared__ ushort Bs[4][128][8];

    const int tid = threadIdx.x;
    const int bm = blockIdx.y * 128;
    const int bn = blockIdx.x * 128;
    const float inv_scale = qp[0];
    const float zp = qp[1];
    const int lane = tid & 63;
    const int wid = tid >> 6;
    const int wm = (wid >> 1) * 64;
    const int wn = (wid & 1) * 64;
    const int l16 = lane & 15;
    const int kg = lane >> 4;
    const int r0 = tid >> 2;
    const int g0 = tid & 3;

    const float* pa0 = x + (size_t)(bm + r0) * K + g0 * 8;
    const float* pa1 = pa0 + (size_t)64 * K;
    const float* pb0 = w + (size_t)(bn + r0) * K + g0 * 8;
    const float* pb1 = pb0 + (size_t)64 * K;

    f32x4 acc[4][4];
#pragma unroll
    for (int i = 0; i < 4; ++i)
#pragma unroll
        for (int j = 0; j < 4; ++j) acc[i][j] = (f32x4){0.f, 0.f, 0.f, 0.f};

    const int nk = K / 32;
    for (int kt = 0; kt < nk; ++kt) {
        float4 a00 = *(const float4*)(pa0 + 0);
        float4 a01 = *(const float4*)(pa0 + 4);
        float4 a10 = *(const float4*)(pa1 + 0);
        float4 a11 = *(const float4*)(pa1 + 4);
        float4 b00 = *(const float4*)(pb0 + 0);
        float4 b01 = *(const float4*)(pb0 + 4);
        float4 b10 = *(const float4*)(pb1 + 0);
        float4 b11 = *(const float4*)(pb1 + 4);
        pa0 += 32; pa1 += 32; pb0 += 32; pb1 += 32;

        bf16x8 qa0 = quant_pack8(a00, a01, inv_scale, zp);
        bf16x8 qa1 = quant_pack8(a10, a11, inv_scale, zp);
        bf16x8 wb0 = cvt_pack8(b00, b01);
        bf16x8 wb1 = cvt_pack8(b10, b11);

        __syncthreads();
        *(bf16x8*)&As[g0][r0][0]      = qa0;
        *(bf16x8*)&As[g0][r0 + 64][0] = qa1;
        *(bf16x8*)&Bs[g0][r0][0]      = wb0;
        *(bf16x8*)&Bs[g0][r0 + 64][0] = wb1;
        __syncthreads();

        bf16x8 af[4], bfr[4];
#pragma unroll
        for (int i = 0; i < 4; ++i)
            af[i] = *(const bf16x8*)&As[kg][wm + i * 16 + l16][0];
#pragma unroll
        for (int j = 0; j < 4; ++j)
            bfr[j] = *(const bf16x8*)&Bs[kg][wn + j * 16 + l16][0];
#pragma unroll
        for (int i = 0; i < 4; ++i)
#pragma unroll
            for (int j = 0; j < 4; ++j)
                acc[i][j] = __builtin_amdgcn_mfma_f32_16x16x32_bf16(af[i], bfr[j], acc[i][j], 0, 0, 0);
    }

#pragma unroll
    for (int j = 0; j < 4; ++j) {
        const int col = bn + wn + j * 16 + l16;
        const float bj = bias[col];
#pragma unroll
        for (int i = 0; i < 4; ++i) {
            const int rowb = bm + wm + i * 16 + kg * 4;
            float* po = out + (size_t)rowb * N + col;
#pragma unroll
            for (int r = 0; r < 4; ++r) po[(size_t)r * N] = acc[i][j][r] + bj;
        }
    }
}

// ---------- launch ----------

extern "C" void kernel_launch(void* const* d_in, const int* in_sizes, int n_in,
                              void* d_out, int out_size, void* d_ws, size_t ws_size,
                              hipStream_t stream) {
    const float* x    = (const float*)d_in[0];
    const float* w    = (const float*)d_in[1];
    const float* bias = (const float*)d_in[2];
    float* out = (float*)d_out;
    char* ws = (char*)d_ws;

    const int N = in_sizes[2];            // 4096
    const int K = in_sizes[1] / N;        // 4096
    const int M = in_sizes[0] / K;        // 8192

    const size_t xq_off = 16384;
    const size_t xq_bytes = (size_t)M * K * 2;
    const size_t wq_off = xq_off + xq_bytes;
    const size_t wq_bytes = (size_t)N * K * 2;
    const size_t need = wq_off + wq_bytes;

    float* hdr  = (float*)ws;
    float* pmin = (float*)(ws + 4096);
    float* pmax = (float*)(ws + 8192);

    const int n4 = in_sizes[0] / 4;
    const bool big_ok = (M % BM == 0) && (N % BN == 0) && (K % BK == 0) && (K / BK >= 2) &&
                        (((M / BM) * (N / BN)) % 8 == 0);

    if (ws_size >= need && big_ok) {
        ushort* xq = (ushort*)(ws + xq_off);
        ushort* wq = (ushort*)(ws + wq_off);

        minmax_partial<<<dim3(1024), dim3(256), 0, stream>>>(x, n4, pmin, pmax);
        finalize_qp<<<dim3(1), dim3(64), 0, stream>>>(pmin, pmax, 1024, hdr);
        quant_x_kernel<<<dim3(2048), dim3(256), 0, stream>>>(x, xq, hdr, in_sizes[0] / 8);
        cvt_w_kernel<<<dim3(1024), dim3(256), 0, stream>>>(w, wq, in_sizes[1] / 8);

        const int nwg = (M / BM) * (N / BN);   // 512
        gemm_bt<<<dim3(nwg), dim3(512), 0, stream>>>(xq, wq, bias, out, M, N, K);
    } else {
        int nb = 1024;
        size_t cap = ws_size / sizeof(float);
        if (cap < (size_t)(4096 + 1024)) {
            long avail = (long)cap - 16;
            nb = avail > 2 ? (int)(avail / 2) : 1;
            pmin = hdr + 16;
            pmax = pmin + nb;
        }
        minmax_partial<<<dim3(nb), dim3(256), 0, stream>>>(x, n4, pmin, pmax);
        finalize_qp<<<dim3(1), dim3(64), 0, stream>>>(pmin, pmax, nb, hdr);
        dim3 grid(N / 128, M / 128);
        qgemm_fused<<<grid, dim3(256), 0, stream>>>(x, w, bias, hdr, out, M, N, K);
    }
}

// Round 8
// 341.344 us; speedup vs baseline: 1.5480x; 1.5480x over previous
//
#include <hip/hip_runtime.h>
#include <hip/hip_bf16.h>

typedef float f32x4 __attribute__((ext_vector_type(4)));
typedef short bf16x8 __attribute__((ext_vector_type(8)));
typedef unsigned short ushort;

// 256^2 8-phase GEMM geometry
#define BM 256
#define BN 256
#define BK 64

// ---------- helpers ----------

__device__ inline ushort f2bf(float f) {
    __hip_bfloat16 h = __float2bfloat16(f);   // RNE
    ushort s;
    __builtin_memcpy(&s, &h, 2);
    return s;
}

__device__ inline bf16x8 quant_pack8(float4 a, float4 b, float inv_scale, float zp) {
    float v[8] = {a.x, a.y, a.z, a.w, b.x, b.y, b.z, b.w};
    union { bf16x8 v8; ushort s[8]; } o;
#pragma unroll
    for (int j = 0; j < 8; ++j) {
        float t = rintf(fmaf(v[j], inv_scale, zp));
        t = fminf(127.0f, fmaxf(-128.0f, t));
        o.s[j] = f2bf(t);
    }
    return o.v8;
}

__device__ inline bf16x8 cvt_pack8(float4 a, float4 b) {
    float v[8] = {a.x, a.y, a.z, a.w, b.x, b.y, b.z, b.w};
    union { bf16x8 v8; ushort s[8]; } o;
#pragma unroll
    for (int j = 0; j < 8; ++j) o.s[j] = f2bf(v[j]);
    return o.v8;
}

#define GLL16(gp, lp)                                                              \
    __builtin_amdgcn_global_load_lds(                                              \
        (const __attribute__((address_space(1))) unsigned int*)(gp),               \
        (__attribute__((address_space(3))) unsigned int*)(lp), 16, 0, 0)

__device__ inline bf16x8 lds_read_b128(const ushort* p) {
    bf16x8 r;
    const __attribute__((address_space(3))) ushort* lp =
        (const __attribute__((address_space(3))) ushort*)p;
    asm volatile("ds_read_b128 %0, %1" : "=&v"(r) : "v"(lp));
    return r;
}

// ---------- kernel 1: per-block min/max partials ----------

__global__ __launch_bounds__(256) void minmax_partial(const float* __restrict__ x, int n4,
                                                      float* __restrict__ pmin,
                                                      float* __restrict__ pmax) {
    float lmin = 3.4e38f, lmax = -3.4e38f;
    const float4* xv = (const float4*)x;
    int stride = gridDim.x * blockDim.x;
    for (int i = blockIdx.x * blockDim.x + threadIdx.x; i < n4; i += stride) {
        float4 v = xv[i];
        lmin = fminf(lmin, fminf(fminf(v.x, v.y), fminf(v.z, v.w)));
        lmax = fmaxf(lmax, fmaxf(fmaxf(v.x, v.y), fmaxf(v.z, v.w)));
    }
#pragma unroll
    for (int off = 32; off > 0; off >>= 1) {
        lmin = fminf(lmin, __shfl_down(lmin, off));
        lmax = fmaxf(lmax, __shfl_down(lmax, off));
    }
    __shared__ float smin[4], smax[4];
    int w = threadIdx.x >> 6;
    if ((threadIdx.x & 63) == 0) { smin[w] = lmin; smax[w] = lmax; }
    __syncthreads();
    if (threadIdx.x == 0) {
        pmin[blockIdx.x] = fminf(fminf(smin[0], smin[1]), fminf(smin[2], smin[3]));
        pmax[blockIdx.x] = fmaxf(fmaxf(smax[0], smax[1]), fmaxf(smax[2], smax[3]));
    }
}

// ---------- kernel 2: finalize scale/zp ----------

__global__ __launch_bounds__(64) void finalize_qp(const float* __restrict__ pmin,
                                                  const float* __restrict__ pmax, int nb,
                                                  float* __restrict__ hdr) {
    float lmin = 3.4e38f, lmax = -3.4e38f;
    for (int i = threadIdx.x; i < nb; i += 64) {
        lmin = fminf(lmin, pmin[i]);
        lmax = fmaxf(lmax, pmax[i]);
    }
#pragma unroll
    for (int off = 32; off > 0; off >>= 1) {
        lmin = fminf(lmin, __shfl_down(lmin, off));
        lmax = fmaxf(lmax, __shfl_down(lmax, off));
    }
    if (threadIdx.x == 0) {
        float scale = (lmax - lmin) / 255.0f;
        float zp = -128.0f - rintf(lmin / scale);
        zp = fminf(127.0f, fmaxf(-128.0f, zp));
        hdr[0] = 1.0f / scale;
        hdr[1] = zp;
    }
}

// ---------- kernel 3a: quantize x -> bf16 codes ----------

__global__ __launch_bounds__(256) void quant_x_kernel(const float* __restrict__ x,
                                                      ushort* __restrict__ xq,
                                                      const float* __restrict__ qp, int n8) {
    const float inv_scale = qp[0];
    const float zp = qp[1];
    int stride = gridDim.x * blockDim.x;
    for (int i = blockIdx.x * blockDim.x + threadIdx.x; i < n8; i += stride) {
        float4 a = *(const float4*)(x + (size_t)i * 8);
        float4 b = *(const float4*)(x + (size_t)i * 8 + 4);
        *(bf16x8*)(xq + (size_t)i * 8) = quant_pack8(a, b, inv_scale, zp);
    }
}

// ---------- kernel 3b: convert W -> bf16 ----------

__global__ __launch_bounds__(256) void cvt_w_kernel(const float* __restrict__ w,
                                                    ushort* __restrict__ wq, int n8) {
    int stride = gridDim.x * blockDim.x;
    for (int i = blockIdx.x * blockDim.x + threadIdx.x; i < n8; i += stride) {
        float4 a = *(const float4*)(w + (size_t)i * 8);
        float4 b = *(const float4*)(w + (size_t)i * 8 + 4);
        *(bf16x8*)(wq + (size_t)i * 8) = cvt_pack8(a, b);
    }
}

// ---------- kernel 4: 256x256 8-phase bf16 MFMA GEMM, COALESCED staging ----------
// C = A(MxK) * B(NxK)^T + bias.
// 512 thr = 8 waves (2x4), wave tile 128x64 = 8x4 frags of 16x16x32.
// LDS per operand per buf: [kh][256 rows][4 slots][8 ushorts] = 32 KB (128 KB total).
// XOR swizzle (both-sides, rule #21): chunk at (row, slot) holds global k-chunk
// kc = slot ^ ((row>>1)&3); gload_lds dest is linear (c*16B, c=row*4+slot), the
// swizzle is pre-applied to the per-lane GLOBAL source. Fragment read slot =
// l4 ^ ((l16>>1)&3) -> uniform 2 words/bank (conflict-free).
// DMA coalescing: 4 consecutive lanes read 4 chunks of ONE row = 64B segments.
// Schedule identical to R4: 4 phases/tile, 2 GLL16/phase staged at lag 7,
// vmcnt(6) per tile boundary, 2 barriers/phase, setprio around MFMA.

__global__ __launch_bounds__(512, 2) void gemm_bt(const ushort* __restrict__ A,
                                                  const ushort* __restrict__ Bw,
                                                  const float* __restrict__ bias,
                                                  float* __restrict__ out,
                                                  int M, int N, int K) {
    __shared__ ushort Alds[2 * 16384];  // [buf][kh][row][slot][8] = 64 KB
    __shared__ ushort Blds[2 * 16384];  // 64 KB

    const int tid = threadIdx.x;
    const int lane = tid & 63;
    const int wid = tid >> 6;

    // bijective XCD swizzle (nwg % 8 == 0 guaranteed by launcher)
    const int nwg = gridDim.x;
    const int cpx = nwg >> 3;
    const int swz = (blockIdx.x & 7) * cpx + (blockIdx.x >> 3);
    const int nbn = N / BN;
    const int bm = (swz / nbn) * BM;
    const int bn = (swz % nbn) * BN;

    const int wm = (wid >> 2) * 128;  // wave row offset
    const int wn = (wid & 3) * 64;    // wave col offset
    const int l16 = lane & 15;
    const int l4 = lane >> 4;

    // ---- DMA per-thread constants (coalesced: 4 lanes per row, 64B segments)
    const int rs = tid >> 2;                        // row 0..127 (+128 for call1)
    const int kc_s = (tid & 3) ^ ((tid >> 3) & 3);  // swizzled source k-chunk
    const ushort* gA = A  + (size_t)(bm + rs) * K + kc_s * 8;
    const ushort* gB = Bw + (size_t)(bn + rs) * K + kc_s * 8;
    const size_t rowJump = (size_t)128 * K;         // call1: rows 128..255
    const int dstT = tid * 8;                       // ushort offset of call0 chunk

    // stage half-tile h: tile th=h>>2, slot=h&3 (0=A-kh0,1=B-kh0,2=A-kh1,3=B-kh1)
#define STAGE_HT(h)                                                          \
    {                                                                        \
        const int th_ = (h) >> 2, sl_ = (h) & 3, kh_ = sl_ >> 1;             \
        const int ko_ = th_ * 64 + kh_ * 32;                                 \
        if (sl_ & 1) {                                                       \
            ushort* d_ = Blds + (th_ & 1) * 16384 + kh_ * 8192 + dstT;       \
            const ushort* s_ = gB + ko_;                                     \
            GLL16(s_, d_);                                                   \
            GLL16(s_ + rowJump, d_ + 4096);                                  \
        } else {                                                             \
            ushort* d_ = Alds + (th_ & 1) * 16384 + kh_ * 8192 + dstT;       \
            const ushort* s_ = gA + ko_;                                     \
            GLL16(s_, d_);                                                   \
            GLL16(s_ + rowJump, d_ + 4096);                                  \
        }                                                                    \
    }

    f32x4 acc[8][4];
#pragma unroll
    for (int i = 0; i < 8; ++i)
#pragma unroll
        for (int j = 0; j < 4; ++j) acc[i][j] = (f32x4){0.f, 0.f, 0.f, 0.f};

    const int nk = K / BK;        // 64 tiles
    const int htot = 4 * nk;

    // ---- prologue: stage h=0..6 (tile0 complete + 3/4 of tile1), wait tile0
#pragma unroll
    for (int h = 0; h < 7; ++h) STAGE_HT(h);
    asm volatile("s_waitcnt vmcnt(6)" ::: "memory");
    __builtin_amdgcn_s_barrier();

    // ---- per-wave read bases: row stride 32 ushorts, swizzled slot per lane
    const int sl = l4 ^ ((l16 >> 1) & 3);
    const ushort* aBase = Alds + (wm + l16) * 32 + sl * 8;
    const ushort* bBase = Blds + (wn + l16) * 32 + sl * 8;

    bf16x8 af[8];
    for (int t = 0; t < nk; ++t) {
        const ushort* Ab = aBase + (t & 1) * 16384;
        const ushort* Bb = bBase + (t & 1) * 16384;
#pragma unroll
        for (int q = 0; q < 4; ++q) {
            const int ks = q >> 1;
            const int fjp = q & 1;
            // phase ds-reads: frag (ks, f) at base + ks*8192 + f*512
            if (fjp == 0) {
#pragma unroll
                for (int fi = 0; fi < 8; ++fi)
                    af[fi] = lds_read_b128(Ab + ks * 8192 + fi * 512);
            }
            bf16x8 b0 = lds_read_b128(Bb + ks * 8192 + (fjp * 2 + 0) * 512);
            bf16x8 b1 = lds_read_b128(Bb + ks * 8192 + (fjp * 2 + 1) * 512);
            // stage one half-tile (lag 7 behind read frontier)
            {
                const int h = 4 * t + q + 7;
                if (h < htot) STAGE_HT(h);
            }
            __builtin_amdgcn_s_barrier();                        // BARRIER1
            asm volatile("s_waitcnt lgkmcnt(0)" ::: "memory");
            __builtin_amdgcn_sched_barrier(0);
            __builtin_amdgcn_s_setprio(1);
#pragma unroll
            for (int fi = 0; fi < 8; ++fi) {
                acc[fi][fjp * 2 + 0] =
                    __builtin_amdgcn_mfma_f32_16x16x32_bf16(af[fi], b0, acc[fi][fjp * 2 + 0], 0, 0, 0);
                acc[fi][fjp * 2 + 1] =
                    __builtin_amdgcn_mfma_f32_16x16x32_bf16(af[fi], b1, acc[fi][fjp * 2 + 1], 0, 0, 0);
            }
            __builtin_amdgcn_s_setprio(0);
            if (q == 3 && t + 1 < nk) {
                if (t + 2 == nk) asm volatile("s_waitcnt vmcnt(0)" ::: "memory");
                else             asm volatile("s_waitcnt vmcnt(6)" ::: "memory");
            }
            __builtin_amdgcn_s_barrier();                        // BARRIER2
        }
    }
#undef STAGE_HT

    // epilogue: C/D layout col = lane&15, row = (lane>>4)*4 + r
#pragma unroll
    for (int fj = 0; fj < 4; ++fj) {
        const int col = bn + wn + fj * 16 + l16;
        const float bj = bias[col];
#pragma unroll
        for (int fi = 0; fi < 8; ++fi) {
            const int rowb = bm + wm + fi * 16 + l4 * 4;
            float* po = out + (size_t)rowb * N + col;
#pragma unroll
            for (int r = 0; r < 4; ++r) po[(size_t)r * N] = acc[fi][fj][r] + bj;
        }
    }
}

// ---------- fallback: fused quantize+GEMM (128^2, used if ws too small) ----------

__global__ __launch_bounds__(256) void qgemm_fused(const float* __restrict__ x,
                                                   const float* __restrict__ w,
                                                   const float* __restrict__ bias,
                                                   const float* __restrict__ qp,
                                                   float* __restrict__ out,
                                                   int M, int N, int K) {
    __shared__ ushort As[4][128][8];
    __shared__ ushort Bs[4][128][8];

    const int tid = threadIdx.x;
    const int bm = blockIdx.y * 128;
    const int bn = blockIdx.x * 128;
    const float inv_scale = qp[0];
    const float zp = qp[1];
    const int lane = tid & 63;
    const int wid = tid >> 6;
    const int wm = (wid >> 1) * 64;
    const int wn = (wid & 1) * 64;
    const int l16 = lane & 15;
    const int kg = lane >> 4;
    const int r0 = tid >> 2;
    const int g0 = tid & 3;

    const float* pa0 = x + (size_t)(bm + r0) * K + g0 * 8;
    const float* pa1 = pa0 + (size_t)64 * K;
    const float* pb0 = w + (size_t)(bn + r0) * K + g0 * 8;
    const float* pb1 = pb0 + (size_t)64 * K;

    f32x4 acc[4][4];
#pragma unroll
    for (int i = 0; i < 4; ++i)
#pragma unroll
        for (int j = 0; j < 4; ++j) acc[i][j] = (f32x4){0.f, 0.f, 0.f, 0.f};

    const int nk = K / 32;
    for (int kt = 0; kt < nk; ++kt) {
        float4 a00 = *(const float4*)(pa0 + 0);
        float4 a01 = *(const float4*)(pa0 + 4);
        float4 a10 = *(const float4*)(pa1 + 0);
        float4 a11 = *(const float4*)(pa1 + 4);
        float4 b00 = *(const float4*)(pb0 + 0);
        float4 b01 = *(const float4*)(pb0 + 4);
        float4 b10 = *(const float4*)(pb1 + 0);
        float4 b11 = *(const float4*)(pb1 + 4);
        pa0 += 32; pa1 += 32; pb0 += 32; pb1 += 32;

        bf16x8 qa0 = quant_pack8(a00, a01, inv_scale, zp);
        bf16x8 qa1 = quant_pack8(a10, a11, inv_scale, zp);
        bf16x8 wb0 = cvt_pack8(b00, b01);
        bf16x8 wb1 = cvt_pack8(b10, b11);

        __syncthreads();
        *(bf16x8*)&As[g0][r0][0]      = qa0;
        *(bf16x8*)&As[g0][r0 + 64][0] = qa1;
        *(bf16x8*)&Bs[g0][r0][0]      = wb0;
        *(bf16x8*)&Bs[g0][r0 + 64][0] = wb1;
        __syncthreads();

        bf16x8 af[4], bfr[4];
#pragma unroll
        for (int i = 0; i < 4; ++i)
            af[i] = *(const bf16x8*)&As[kg][wm + i * 16 + l16][0];
#pragma unroll
        for (int j = 0; j < 4; ++j)
            bfr[j] = *(const bf16x8*)&Bs[kg][wn + j * 16 + l16][0];
#pragma unroll
        for (int i = 0; i < 4; ++i)
#pragma unroll
            for (int j = 0; j < 4; ++j)
                acc[i][j] = __builtin_amdgcn_mfma_f32_16x16x32_bf16(af[i], bfr[j], acc[i][j], 0, 0, 0);
    }

#pragma unroll
    for (int j = 0; j < 4; ++j) {
        const int col = bn + wn + j * 16 + l16;
        const float bj = bias[col];
#pragma unroll
        for (int i = 0; i < 4; ++i) {
            const int rowb = bm + wm + i * 16 + kg * 4;
            float* po = out + (size_t)rowb * N + col;
#pragma unroll
            for (int r = 0; r < 4; ++r) po[(size_t)r * N] = acc[i][j][r] + bj;
        }
    }
}

// ---------- launch ----------

extern "C" void kernel_launch(void* const* d_in, const int* in_sizes, int n_in,
                              void* d_out, int out_size, void* d_ws, size_t ws_size,
                              hipStream_t stream) {
    const float* x    = (const float*)d_in[0];
    const float* w    = (const float*)d_in[1];
    const float* bias = (const float*)d_in[2];
    float* out = (float*)d_out;
    char* ws = (char*)d_ws;

    const int N = in_sizes[2];            // 4096
    const int K = in_sizes[1] / N;        // 4096
    const int M = in_sizes[0] / K;        // 8192

    const size_t xq_off = 16384;
    const size_t xq_bytes = (size_t)M * K * 2;
    const size_t wq_off = xq_off + xq_bytes;
    const size_t wq_bytes = (size_t)N * K * 2;
    const size_t need = wq_off + wq_bytes;

    float* hdr  = (float*)ws;
    float* pmin = (float*)(ws + 4096);
    float* pmax = (float*)(ws + 8192);

    const int n4 = in_sizes[0] / 4;
    const bool big_ok = (M % BM == 0) && (N % BN == 0) && (K % BK == 0) && (K / BK >= 2) &&
                        (((M / BM) * (N / BN)) % 8 == 0);

    if (ws_size >= need && big_ok) {
        ushort* xq = (ushort*)(ws + xq_off);
        ushort* wq = (ushort*)(ws + wq_off);

        minmax_partial<<<dim3(1024), dim3(256), 0, stream>>>(x, n4, pmin, pmax);
        finalize_qp<<<dim3(1), dim3(64), 0, stream>>>(pmin, pmax, 1024, hdr);
        quant_x_kernel<<<dim3(2048), dim3(256), 0, stream>>>(x, xq, hdr, in_sizes[0] / 8);
        cvt_w_kernel<<<dim3(1024), dim3(256), 0, stream>>>(w, wq, in_sizes[1] / 8);

        const int nwg = (M / BM) * (N / BN);   // 512
        gemm_bt<<<dim3(nwg), dim3(512), 0, stream>>>(xq, wq, bias, out, M, N, K);
    } else {
        int nb = 1024;
        size_t cap = ws_size / sizeof(float);
        if (cap < (size_t)(4096 + 1024)) {
            long avail = (long)cap - 16;
            nb = avail > 2 ? (int)(avail / 2) : 1;
            pmin = hdr + 16;
            pmax = pmin + nb;
        }
        minmax_partial<<<dim3(nb), dim3(256), 0, stream>>>(x, n4, pmin, pmax);
        finalize_qp<<<dim3(1), dim3(64), 0, stream>>>(pmin, pmax, nb, hdr);
        dim3 grid(N / 128, M / 128);
        qgemm_fused<<<grid, dim3(256), 0, stream>>>(x, w, bias, hdr, out, M, N, K);
    }
}

// Round 9
// 332.635 us; speedup vs baseline: 1.5885x; 1.0262x over previous
//
#include <hip/hip_runtime.h>
#include <hip/hip_bf16.h>

typedef float f32x4 __attribute__((ext_vector_type(4)));
typedef short bf16x8 __attribute__((ext_vector_type(8)));
typedef unsigned short ushort;

// 256^2 8-phase GEMM geometry
#define BM 256
#define BN 256
#define BK 64

// ---------- helpers ----------

__device__ inline ushort f2bf(float f) {
    __hip_bfloat16 h = __float2bfloat16(f);   // RNE
    ushort s;
    __builtin_memcpy(&s, &h, 2);
    return s;
}

__device__ inline bf16x8 quant_pack8(float4 a, float4 b, float inv_scale, float zp) {
    float v[8] = {a.x, a.y, a.z, a.w, b.x, b.y, b.z, b.w};
    union { bf16x8 v8; ushort s[8]; } o;
#pragma unroll
    for (int j = 0; j < 8; ++j) {
        float t = rintf(fmaf(v[j], inv_scale, zp));
        t = fminf(127.0f, fmaxf(-128.0f, t));
        o.s[j] = f2bf(t);
    }
    return o.v8;
}

__device__ inline bf16x8 cvt_pack8(float4 a, float4 b) {
    float v[8] = {a.x, a.y, a.z, a.w, b.x, b.y, b.z, b.w};
    union { bf16x8 v8; ushort s[8]; } o;
#pragma unroll
    for (int j = 0; j < 8; ++j) o.s[j] = f2bf(v[j]);
    return o.v8;
}

#define GLL16(gp, lp)                                                              \
    __builtin_amdgcn_global_load_lds(                                              \
        (const __attribute__((address_space(1))) unsigned int*)(gp),               \
        (__attribute__((address_space(3))) unsigned int*)(lp), 16, 0, 0)

__device__ inline bf16x8 lds_read_b128(const ushort* p) {
    bf16x8 r;
    const __attribute__((address_space(3))) ushort* lp =
        (const __attribute__((address_space(3))) ushort*)p;
    asm volatile("ds_read_b128 %0, %1" : "=&v"(r) : "v"(lp));
    return r;
}

// ---------- kernel 1: per-block min/max partials ----------

__global__ __launch_bounds__(256) void minmax_partial(const float* __restrict__ x, int n4,
                                                      float* __restrict__ pmin,
                                                      float* __restrict__ pmax) {
    float lmin = 3.4e38f, lmax = -3.4e38f;
    const float4* xv = (const float4*)x;
    int stride = gridDim.x * blockDim.x;
    for (int i = blockIdx.x * blockDim.x + threadIdx.x; i < n4; i += stride) {
        float4 v = xv[i];
        lmin = fminf(lmin, fminf(fminf(v.x, v.y), fminf(v.z, v.w)));
        lmax = fmaxf(lmax, fmaxf(fmaxf(v.x, v.y), fmaxf(v.z, v.w)));
    }
#pragma unroll
    for (int off = 32; off > 0; off >>= 1) {
        lmin = fminf(lmin, __shfl_down(lmin, off));
        lmax = fmaxf(lmax, __shfl_down(lmax, off));
    }
    __shared__ float smin[4], smax[4];
    int w = threadIdx.x >> 6;
    if ((threadIdx.x & 63) == 0) { smin[w] = lmin; smax[w] = lmax; }
    __syncthreads();
    if (threadIdx.x == 0) {
        pmin[blockIdx.x] = fminf(fminf(smin[0], smin[1]), fminf(smin[2], smin[3]));
        pmax[blockIdx.x] = fmaxf(fmaxf(smax[0], smax[1]), fmaxf(smax[2], smax[3]));
    }
}

// ---------- kernel 2: finalize scale/zp ----------

__global__ __launch_bounds__(64) void finalize_qp(const float* __restrict__ pmin,
                                                  const float* __restrict__ pmax, int nb,
                                                  float* __restrict__ hdr) {
    float lmin = 3.4e38f, lmax = -3.4e38f;
    for (int i = threadIdx.x; i < nb; i += 64) {
        lmin = fminf(lmin, pmin[i]);
        lmax = fmaxf(lmax, pmax[i]);
    }
#pragma unroll
    for (int off = 32; off > 0; off >>= 1) {
        lmin = fminf(lmin, __shfl_down(lmin, off));
        lmax = fmaxf(lmax, __shfl_down(lmax, off));
    }
    if (threadIdx.x == 0) {
        float scale = (lmax - lmin) / 255.0f;
        float zp = -128.0f - rintf(lmin / scale);
        zp = fminf(127.0f, fmaxf(-128.0f, zp));
        hdr[0] = 1.0f / scale;
        hdr[1] = zp;
    }
}

// ---------- kernel 3a: quantize x -> bf16 codes ----------

__global__ __launch_bounds__(256) void quant_x_kernel(const float* __restrict__ x,
                                                      ushort* __restrict__ xq,
                                                      const float* __restrict__ qp, int n8) {
    const float inv_scale = qp[0];
    const float zp = qp[1];
    int stride = gridDim.x * blockDim.x;
    for (int i = blockIdx.x * blockDim.x + threadIdx.x; i < n8; i += stride) {
        float4 a = *(const float4*)(x + (size_t)i * 8);
        float4 b = *(const float4*)(x + (size_t)i * 8 + 4);
        *(bf16x8*)(xq + (size_t)i * 8) = quant_pack8(a, b, inv_scale, zp);
    }
}

// ---------- kernel 3b: convert W -> bf16 ----------

__global__ __launch_bounds__(256) void cvt_w_kernel(const float* __restrict__ w,
                                                    ushort* __restrict__ wq, int n8) {
    int stride = gridDim.x * blockDim.x;
    for (int i = blockIdx.x * blockDim.x + threadIdx.x; i < n8; i += stride) {
        float4 a = *(const float4*)(w + (size_t)i * 8);
        float4 b = *(const float4*)(w + (size_t)i * 8 + 4);
        *(bf16x8*)(wq + (size_t)i * 8) = cvt_pack8(a, b);
    }
}

// ---------- kernel 4: 256x256 8-phase bf16 MFMA GEMM, coalesced staging ----------
// Identical to R8 EXCEPT: BARRIER1 removed (one barrier per phase).
// Safety: a wave issues phase-q staging only after passing barrier q-1; every
// wave arriving at barrier q-1 already executed its lgkmcnt(0) (program order),
// so all reads of the overwritten region are complete. The per-phase lgkmcnt(0)
// waits only own reads. Cross-wave effect: late waves' DS bursts now overlap
// early waves' MFMA clusters instead of double-rendezvousing every 16 MFMAs.

__global__ __launch_bounds__(512, 2) void gemm_bt(const ushort* __restrict__ A,
                                                  const ushort* __restrict__ Bw,
                                                  const float* __restrict__ bias,
                                                  float* __restrict__ out,
                                                  int M, int N, int K) {
    __shared__ ushort Alds[2 * 16384];  // [buf][kh][row][slot][8] = 64 KB
    __shared__ ushort Blds[2 * 16384];  // 64 KB

    const int tid = threadIdx.x;
    const int lane = tid & 63;
    const int wid = tid >> 6;

    // bijective XCD swizzle (nwg % 8 == 0 guaranteed by launcher)
    const int nwg = gridDim.x;
    const int cpx = nwg >> 3;
    const int swz = (blockIdx.x & 7) * cpx + (blockIdx.x >> 3);
    const int nbn = N / BN;
    const int bm = (swz / nbn) * BM;
    const int bn = (swz % nbn) * BN;

    const int wm = (wid >> 2) * 128;  // wave row offset
    const int wn = (wid & 3) * 64;    // wave col offset
    const int l16 = lane & 15;
    const int l4 = lane >> 4;

    // ---- DMA per-thread constants (coalesced: 4 lanes per row, 64B segments)
    const int rs = tid >> 2;                        // row 0..127 (+128 for call1)
    const int kc_s = (tid & 3) ^ ((tid >> 3) & 3);  // swizzled source k-chunk
    const ushort* gA = A  + (size_t)(bm + rs) * K + kc_s * 8;
    const ushort* gB = Bw + (size_t)(bn + rs) * K + kc_s * 8;
    const size_t rowJump = (size_t)128 * K;         // call1: rows 128..255
    const int dstT = tid * 8;                       // ushort offset of call0 chunk

    // stage half-tile h: tile th=h>>2, slot=h&3 (0=A-kh0,1=B-kh0,2=A-kh1,3=B-kh1)
#define STAGE_HT(h)                                                          \
    {                                                                        \
        const int th_ = (h) >> 2, sl_ = (h) & 3, kh_ = sl_ >> 1;             \
        const int ko_ = th_ * 64 + kh_ * 32;                                 \
        if (sl_ & 1) {                                                       \
            ushort* d_ = Blds + (th_ & 1) * 16384 + kh_ * 8192 + dstT;       \
            const ushort* s_ = gB + ko_;                                     \
            GLL16(s_, d_);                                                   \
            GLL16(s_ + rowJump, d_ + 4096);                                  \
        } else {                                                             \
            ushort* d_ = Alds + (th_ & 1) * 16384 + kh_ * 8192 + dstT;       \
            const ushort* s_ = gA + ko_;                                     \
            GLL16(s_, d_);                                                   \
            GLL16(s_ + rowJump, d_ + 4096);                                  \
        }                                                                    \
    }

    f32x4 acc[8][4];
#pragma unroll
    for (int i = 0; i < 8; ++i)
#pragma unroll
        for (int j = 0; j < 4; ++j) acc[i][j] = (f32x4){0.f, 0.f, 0.f, 0.f};

    const int nk = K / BK;        // 64 tiles
    const int htot = 4 * nk;

    // ---- prologue: stage h=0..6 (tile0 complete + 3/4 of tile1), wait tile0
#pragma unroll
    for (int h = 0; h < 7; ++h) STAGE_HT(h);
    asm volatile("s_waitcnt vmcnt(6)" ::: "memory");
    __builtin_amdgcn_s_barrier();

    // ---- per-wave read bases: row stride 32 ushorts, swizzled slot per lane
    const int sl = l4 ^ ((l16 >> 1) & 3);
    const ushort* aBase = Alds + (wm + l16) * 32 + sl * 8;
    const ushort* bBase = Blds + (wn + l16) * 32 + sl * 8;

    bf16x8 af[8];
    for (int t = 0; t < nk; ++t) {
        const ushort* Ab = aBase + (t & 1) * 16384;
        const ushort* Bb = bBase + (t & 1) * 16384;
#pragma unroll
        for (int q = 0; q < 4; ++q) {
            const int ks = q >> 1;
            const int fjp = q & 1;
            // phase ds-reads: frag (ks, f) at base + ks*8192 + f*512
            if (fjp == 0) {
#pragma unroll
                for (int fi = 0; fi < 8; ++fi)
                    af[fi] = lds_read_b128(Ab + ks * 8192 + fi * 512);
            }
            bf16x8 b0 = lds_read_b128(Bb + ks * 8192 + (fjp * 2 + 0) * 512);
            bf16x8 b1 = lds_read_b128(Bb + ks * 8192 + (fjp * 2 + 1) * 512);
            // stage one half-tile (lag 7 behind read frontier)
            {
                const int h = 4 * t + q + 7;
                if (h < htot) STAGE_HT(h);
            }
            asm volatile("s_waitcnt lgkmcnt(0)" ::: "memory");   // own reads done
            __builtin_amdgcn_sched_barrier(0);
            __builtin_amdgcn_s_setprio(1);
#pragma unroll
            for (int fi = 0; fi < 8; ++fi) {
                acc[fi][fjp * 2 + 0] =
                    __builtin_amdgcn_mfma_f32_16x16x32_bf16(af[fi], b0, acc[fi][fjp * 2 + 0], 0, 0, 0);
                acc[fi][fjp * 2 + 1] =
                    __builtin_amdgcn_mfma_f32_16x16x32_bf16(af[fi], b1, acc[fi][fjp * 2 + 1], 0, 0, 0);
            }
            __builtin_amdgcn_s_setprio(0);
            if (q == 3 && t + 1 < nk) {
                if (t + 2 == nk) asm volatile("s_waitcnt vmcnt(0)" ::: "memory");
                else             asm volatile("s_waitcnt vmcnt(6)" ::: "memory");
            }
            __builtin_amdgcn_s_barrier();                        // phase barrier
        }
    }
#undef STAGE_HT

    // epilogue: C/D layout col = lane&15, row = (lane>>4)*4 + r
#pragma unroll
    for (int fj = 0; fj < 4; ++fj) {
        const int col = bn + wn + fj * 16 + l16;
        const float bj = bias[col];
#pragma unroll
        for (int fi = 0; fi < 8; ++fi) {
            const int rowb = bm + wm + fi * 16 + l4 * 4;
            float* po = out + (size_t)rowb * N + col;
#pragma unroll
            for (int r = 0; r < 4; ++r) po[(size_t)r * N] = acc[fi][fj][r] + bj;
        }
    }
}

// ---------- fallback: fused quantize+GEMM (128^2, used if ws too small) ----------

__global__ __launch_bounds__(256) void qgemm_fused(const float* __restrict__ x,
                                                   const float* __restrict__ w,
                                                   const float* __restrict__ bias,
                                                   const float* __restrict__ qp,
                                                   float* __restrict__ out,
                                                   int M, int N, int K) {
    __shared__ ushort As[4][128][8];
    __shared__ ushort Bs[4][128][8];

    const int tid = threadIdx.x;
    const int bm = blockIdx.y * 128;
    const int bn = blockIdx.x * 128;
    const float inv_scale = qp[0];
    const float zp = qp[1];
    const int lane = tid & 63;
    const int wid = tid >> 6;
    const int wm = (wid >> 1) * 64;
    const int wn = (wid & 1) * 64;
    const int l16 = lane & 15;
    const int kg = lane >> 4;
    const int r0 = tid >> 2;
    const int g0 = tid & 3;

    const float* pa0 = x + (size_t)(bm + r0) * K + g0 * 8;
    const float* pa1 = pa0 + (size_t)64 * K;
    const float* pb0 = w + (size_t)(bn + r0) * K + g0 * 8;
    const float* pb1 = pb0 + (size_t)64 * K;

    f32x4 acc[4][4];
#pragma unroll
    for (int i = 0; i < 4; ++i)
#pragma unroll
        for (int j = 0; j < 4; ++j) acc[i][j] = (f32x4){0.f, 0.f, 0.f, 0.f};

    const int nk = K / 32;
    for (int kt = 0; kt < nk; ++kt) {
        float4 a00 = *(const float4*)(pa0 + 0);
        float4 a01 = *(const float4*)(pa0 + 4);
        float4 a10 = *(const float4*)(pa1 + 0);
        float4 a11 = *(const float4*)(pa1 + 4);
        float4 b00 = *(const float4*)(pb0 + 0);
        float4 b01 = *(const float4*)(pb0 + 4);
        float4 b10 = *(const float4*)(pb1 + 0);
        float4 b11 = *(const float4*)(pb1 + 4);
        pa0 += 32; pa1 += 32; pb0 += 32; pb1 += 32;

        bf16x8 qa0 = quant_pack8(a00, a01, inv_scale, zp);
        bf16x8 qa1 = quant_pack8(a10, a11, inv_scale, zp);
        bf16x8 wb0 = cvt_pack8(b00, b01);
        bf16x8 wb1 = cvt_pack8(b10, b11);

        __syncthreads();
        *(bf16x8*)&As[g0][r0][0]      = qa0;
        *(bf16x8*)&As[g0][r0 + 64][0] = qa1;
        *(bf16x8*)&Bs[g0][r0][0]      = wb0;
        *(bf16x8*)&Bs[g0][r0 + 64][0] = wb1;
        __syncthreads();

        bf16x8 af[4], bfr[4];
#pragma unroll
        for (int i = 0; i < 4; ++i)
            af[i] = *(const bf16x8*)&As[kg][wm + i * 16 + l16][0];
#pragma unroll
        for (int j = 0; j < 4; ++j)
            bfr[j] = *(const bf16x8*)&Bs[kg][wn + j * 16 + l16][0];
#pragma unroll
        for (int i = 0; i < 4; ++i)
#pragma unroll
            for (int j = 0; j < 4; ++j)
                acc[i][j] = __builtin_amdgcn_mfma_f32_16x16x32_bf16(af[i], bfr[j], acc[i][j], 0, 0, 0);
    }

#pragma unroll
    for (int j = 0; j < 4; ++j) {
        const int col = bn + wn + j * 16 + l16;
        const float bj = bias[col];
#pragma unroll
        for (int i = 0; i < 4; ++i) {
            const int rowb = bm + wm + i * 16 + kg * 4;
            float* po = out + (size_t)rowb * N + col;
#pragma unroll
            for (int r = 0; r < 4; ++r) po[(size_t)r * N] = acc[i][j][r] + bj;
        }
    }
}

// ---------- launch ----------

extern "C" void kernel_launch(void* const* d_in, const int* in_sizes, int n_in,
                              void* d_out, int out_size, void* d_ws, size_t ws_size,
                              hipStream_t stream) {
    const float* x    = (const float*)d_in[0];
    const float* w    = (const float*)d_in[1];
    const float* bias = (const float*)d_in[2];
    float* out = (float*)d_out;
    char* ws = (char*)d_ws;

    const int N = in_sizes[2];            // 4096
    const int K = in_sizes[1] / N;        // 4096
    const int M = in_sizes[0] / K;        // 8192

    const size_t xq_off = 16384;
    const size_t xq_bytes = (size_t)M * K * 2;
    const size_t wq_off = xq_off + xq_bytes;
    const size_t wq_bytes = (size_t)N * K * 2;
    const size_t need = wq_off + wq_bytes;

    float* hdr  = (float*)ws;
    float* pmin = (float*)(ws + 4096);
    float* pmax = (float*)(ws + 8192);

    const int n4 = in_sizes[0] / 4;
    const bool big_ok = (M % BM == 0) && (N % BN == 0) && (K % BK == 0) && (K / BK >= 2) &&
                        (((M / BM) * (N / BN)) % 8 == 0);

    if (ws_size >= need && big_ok) {
        ushort* xq = (ushort*)(ws + xq_off);
        ushort* wq = (ushort*)(ws + wq_off);

        minmax_partial<<<dim3(1024), dim3(256), 0, stream>>>(x, n4, pmin, pmax);
        finalize_qp<<<dim3(1), dim3(64), 0, stream>>>(pmin, pmax, 1024, hdr);
        quant_x_kernel<<<dim3(2048), dim3(256), 0, stream>>>(x, xq, hdr, in_sizes[0] / 8);
        cvt_w_kernel<<<dim3(1024), dim3(256), 0, stream>>>(w, wq, in_sizes[1] / 8);

        const int nwg = (M / BM) * (N / BN);   // 512
        gemm_bt<<<dim3(nwg), dim3(512), 0, stream>>>(xq, wq, bias, out, M, N, K);
    } else {
        int nb = 1024;
        size_t cap = ws_size / sizeof(float);
        if (cap < (size_t)(4096 + 1024)) {
            long avail = (long)cap - 16;
            nb = avail > 2 ? (int)(avail / 2) : 1;
            pmin = hdr + 16;
            pmax = pmin + nb;
        }
        minmax_partial<<<dim3(nb), dim3(256), 0, stream>>>(x, n4, pmin, pmax);
        finalize_qp<<<dim3(1), dim3(64), 0, stream>>>(pmin, pmax, nb, hdr);
        dim3 grid(N / 128, M / 128);
        qgemm_fused<<<grid, dim3(256), 0, stream>>>(x, w, bias, hdr, out, M, N, K);
    }
}